// Round 9
// baseline (203.898 us; speedup 1.0000x reference)
//
#include <hip/hip_runtime.h>
#include <hip/hip_bf16.h>
#include <math.h>

#define NTOK 512      // N
#define BATCH 2
#define HID 256
#define HEADS 4
#define HD 64
#define NEG_INF -1e9f

typedef short bf16x8 __attribute__((ext_vector_type(8)));
typedef short bf16x4 __attribute__((ext_vector_type(4)));
typedef float f32x4 __attribute__((ext_vector_type(4)));

__device__ __forceinline__ short f2bf(float f) {
    union { __hip_bfloat16 h; short s; } u;
    u.h = __float2bfloat16(f);
    return u.s;
}

// tanh-form gelu, exp2+rcp based (5 VALU + 2 trans):
//   gelu(x) = x - x * rcp(exp2(x*(2.3021176 + 0.10293919*x^2)) + 1)
__device__ __forceinline__ float fast_gelu(float x) {
    const float x2 = x * x;
    const float u2 = x * fmaf(x2, 0.10293919f, 2.3021176f);
    const float e = __builtin_amdgcn_exp2f(u2);
    const float r = __builtin_amdgcn_rcpf(e + 1.0f);
    return fmaf(-x, r, x);
}

// ---------------------------------------------------------------------------
// Stage A: fused 5-way projection GEMM.  Y = X @ W (+bias). ALL outputs
//   row-major now (B no longer transposed -> no scattered stores).
// ---------------------------------------------------------------------------
__global__ __launch_bounds__(256) void pga_proj5(
    const float* __restrict__ x,
    const float* __restrict__ Wq, const float* __restrict__ bq,
    const float* __restrict__ Wk, const float* __restrict__ bk,
    const float* __restrict__ Wv, const float* __restrict__ bv,
    const float* __restrict__ Wp1, const float* __restrict__ bp1,
    float* __restrict__ Q, float* __restrict__ K, float* __restrict__ V,
    float* __restrict__ A, float* __restrict__ Brow)
{
    __shared__ float xs[16][HID];
    const int m0 = blockIdx.x * 16;
    const int which = blockIdx.y;
    const int t = threadIdx.x;
    const int cg = t & 63;
    const int rg = t >> 6;

    {
        const float4* xg = (const float4*)(x + m0 * HID);
        float4* xsv = (float4*)xs;
        #pragma unroll
        for (int k = 0; k < 4; ++k) xsv[t + 256 * k] = xg[t + 256 * k];
    }
    __syncthreads();

    const float* W; const float* bvec; float* out;
    switch (which) {
        case 0: W = Wq; bvec = bq; out = Q; break;
        case 1: W = Wk; bvec = bk; out = K; break;
        case 2: W = Wv; bvec = bv; out = V; break;
        case 3: W = Wp1; bvec = bp1; out = A; break;
        default: W = Wp1 + HID * HID; bvec = nullptr; out = Brow; break;
    }

    float4 bias4 = make_float4(0.f, 0.f, 0.f, 0.f);
    if (bvec) bias4 = ((const float4*)bvec)[cg];
    float4 acc[4] = {bias4, bias4, bias4, bias4};

    const float4* W4 = (const float4*)W;
    for (int kq = 0; kq < 64; ++kq) {
        const float4 w0 = W4[(4 * kq + 0) * 64 + cg];
        const float4 w1 = W4[(4 * kq + 1) * 64 + cg];
        const float4 w2 = W4[(4 * kq + 2) * 64 + cg];
        const float4 w3 = W4[(4 * kq + 3) * 64 + cg];
        #pragma unroll
        for (int r = 0; r < 4; ++r) {
            const float4 xv = ((const float4*)xs[4 * rg + r])[kq];
            acc[r].x = fmaf(xv.x, w0.x, fmaf(xv.y, w1.x, fmaf(xv.z, w2.x, fmaf(xv.w, w3.x, acc[r].x))));
            acc[r].y = fmaf(xv.x, w0.y, fmaf(xv.y, w1.y, fmaf(xv.z, w2.y, fmaf(xv.w, w3.y, acc[r].y))));
            acc[r].z = fmaf(xv.x, w0.z, fmaf(xv.y, w1.z, fmaf(xv.z, w2.z, fmaf(xv.w, w3.z, acc[r].z))));
            acc[r].w = fmaf(xv.x, w0.w, fmaf(xv.y, w1.w, fmaf(xv.z, w2.w, fmaf(xv.w, w3.w, acc[r].w))));
        }
    }

    #pragma unroll
    for (int r = 0; r < 4; ++r)
        ((float4*)(out + (size_t)(m0 + 4 * rg + r) * HID))[cg] = acc[r];
}

// ---------------------------------------------------------------------------
// Stage B: physics bias, ROW-GRANULAR sparse. One (b,i) row per 320-thread
//   block. 16 lanes per valid pair (4 pairs/wave, 20/block-iter); lane owns
//   16 d's (4x float4): B is row-major so every load inst reads 4 contiguous
//   256B rows -> dense lines (kills the [d][j]-layout gather: 96->20
//   lines/pair, the measured 47us TA wall). a-row and the full Wp2 table
//   live in persistent REGISTERS (no LDS pipe -- R5 lesson; loaded once).
//   Reduce = 4 shfl_xor steps within the 16-lane group.
//   Dense NEG_INF prefill kept: biasg carries the adjacency mask for attn.
// ---------------------------------------------------------------------------
__global__ __launch_bounds__(320) void pga_bias(
    const float* __restrict__ A, const float* __restrict__ Brow,
    const float* __restrict__ Wp2, const float* __restrict__ bp2,
    const int* __restrict__ adj, float* __restrict__ biasg)
{
    __shared__ short jlist[NTOK];
    __shared__ int ccnt[8];

    const int t = threadIdx.x;          // 0..319
    const int b = blockIdx.x >> 9;
    const int i = blockIdx.x & 511;
    const int w = t >> 6, lane = t & 63;
    const int l15 = lane & 15, grp = lane >> 4;
    const unsigned long long ltm = (1ull << lane) - 1ull;

    // ---- dense NEG_INF prefill of row i in all 4 head planes ----
    {
        float* o0 = biasg + (((size_t)b * HEADS) * NTOK + i) * NTOK;
        #pragma unroll
        for (int hh = 0; hh < 4; ++hh) {
            float* oh = o0 + (size_t)hh * NTOK * NTOK;
            for (int jj = t; jj < NTOK; jj += 320) oh[jj] = NEG_INF;
        }
    }

    // ---- persistent per-lane tables: d = c*64 + l15*4 + k ----
    const float4* wp4 = (const float4*)Wp2;
    const float4* arow4 = (const float4*)(A + ((size_t)(b * NTOK) + i) * HID);
    float4 av[4], wpr[4][4];
    #pragma unroll
    for (int c = 0; c < 4; ++c) {
        av[c] = arow4[c * 16 + l15];
        #pragma unroll
        for (int k = 0; k < 4; ++k)
            wpr[c][k] = wp4[c * 64 + l15 * 4 + k];
    }

    // ---- ordered ballot compaction of row i ----
    const int c0 = w, c1 = w + 5;
    bool m0 = adj[i * NTOK + c0 * 64 + lane] > 0;
    bool m1 = (c1 < 8) ? (adj[i * NTOK + c1 * 64 + lane] > 0) : false;
    const unsigned long long bm0 = __ballot(m0);
    const unsigned long long bm1 = __ballot(m1);
    if (lane == 0) {
        ccnt[c0] = __popcll(bm0);
        if (c1 < 8) ccnt[c1] = __popcll(bm1);
    }
    __syncthreads();

    int pref0 = 0, pref1 = 0, tot = 0;
    #pragma unroll
    for (int c = 0; c < 8; ++c) {
        if (c == c0) pref0 = tot;
        if (c == c1) pref1 = tot;
        tot += ccnt[c];
    }
    if (m0) jlist[pref0 + __popcll(bm0 & ltm)] = (short)(c0 * 64 + lane);
    if (c1 < 8 && m1) jlist[pref1 + __popcll(bm1 & ltm)] = (short)(c1 * 64 + lane);
    __syncthreads();   // orders prefill stores before overwrites too

    const float4 bp = *(const float4*)bp2;

#define GELSTEP(AVC, BVC, WV) do {                                    \
        const float xg_ = (AVC) + (BVC);                              \
        const float g_ = fast_gelu(xg_);                              \
        p0 = fmaf(g_, (WV).x, p0); p1 = fmaf(g_, (WV).y, p1);         \
        p2 = fmaf(g_, (WV).z, p2); p3 = fmaf(g_, (WV).w, p3);         \
    } while (0)

    for (int base = w * 4; base < tot; base += 20) {
        const int myidx = base + grp;
        const int j = jlist[(myidx < tot) ? myidx : (tot - 1)];
        const float4* brow = (const float4*)(Brow + ((size_t)(b * NTOK) + j) * HID);
        float4 bv0 = brow[0 * 16 + l15];
        float4 bv1 = brow[1 * 16 + l15];
        float4 bv2 = brow[2 * 16 + l15];
        float4 bv3 = brow[3 * 16 + l15];

        float p0 = 0.f, p1 = 0.f, p2 = 0.f, p3 = 0.f;
        GELSTEP(av[0].x, bv0.x, wpr[0][0]); GELSTEP(av[0].y, bv0.y, wpr[0][1]);
        GELSTEP(av[0].z, bv0.z, wpr[0][2]); GELSTEP(av[0].w, bv0.w, wpr[0][3]);
        GELSTEP(av[1].x, bv1.x, wpr[1][0]); GELSTEP(av[1].y, bv1.y, wpr[1][1]);
        GELSTEP(av[1].z, bv1.z, wpr[1][2]); GELSTEP(av[1].w, bv1.w, wpr[1][3]);
        GELSTEP(av[2].x, bv2.x, wpr[2][0]); GELSTEP(av[2].y, bv2.y, wpr[2][1]);
        GELSTEP(av[2].z, bv2.z, wpr[2][2]); GELSTEP(av[2].w, bv2.w, wpr[2][3]);
        GELSTEP(av[3].x, bv3.x, wpr[3][0]); GELSTEP(av[3].y, bv3.y, wpr[3][1]);
        GELSTEP(av[3].z, bv3.z, wpr[3][2]); GELSTEP(av[3].w, bv3.w, wpr[3][3]);

        #pragma unroll
        for (int off = 1; off < 16; off <<= 1) {
            p0 += __shfl_xor(p0, off, 64);
            p1 += __shfl_xor(p1, off, 64);
            p2 += __shfl_xor(p2, off, 64);
            p3 += __shfl_xor(p3, off, 64);
        }

        if (myidx < tot && l15 < 4) {
            const float val = (l15 == 0) ? p0 + bp.x :
                              (l15 == 1) ? p1 + bp.y :
                              (l15 == 2) ? p2 + bp.z : p3 + bp.w;
            biasg[(((size_t)(b * HEADS + l15)) * NTOK + i) * NTOK + j] = val;
        }
    }
#undef GELSTEP
}

// ---------------------------------------------------------------------------
// Stage C: MFMA attention with INTRA-BLOCK j-split + merge (R8 form, frozen).
// ---------------------------------------------------------------------------
#define KT_STRIDE 72
#define PL_STRIDE 136

__global__ __launch_bounds__(256) void pga_attn(
    const float* __restrict__ Q, const float* __restrict__ K,
    const float* __restrict__ V, const float* __restrict__ biasg,
    float* __restrict__ Og)
{
    __shared__ short Kt[4][128 * KT_STRIDE];
    __shared__ short Pl[4][16 * PL_STRIDE];
    __shared__ float Om[4][16][68];
    __shared__ float2 ml[4][16];

    const int blk = blockIdx.x;
    const int qt = blk & 31;
    const int h  = (blk >> 5) & 3;
    const int b  = blk >> 7;
    const int t = threadIdx.x;
    const int w = t >> 6;
    const int lane = t & 63;
    const int ln15 = lane & 15;
    const int quad = lane >> 4;

    const int i0 = qt * 16;
    const int j0 = w * 128;

    float bpre[8][4];
    {
        const float* bgb = biasg + ((size_t)(b * HEADS + h)) * NTOK * NTOK;
        #pragma unroll
        for (int nt = 0; nt < 8; ++nt) {
            const int j = j0 + nt * 16 + ln15;
            #pragma unroll
            for (int r = 0; r < 4; ++r)
                bpre[nt][r] = bgb[(size_t)(i0 + quad * 4 + r) * NTOK + j];
        }
    }

    bf16x8 aq0, aq1;
    {
        const float* qrow = Q + ((size_t)(b * NTOK) + i0 + ln15) * HID + h * HD;
        const float4 q0 = ((const float4*)qrow)[quad * 2];
        const float4 q1 = ((const float4*)qrow)[quad * 2 + 1];
        const float4 q2 = ((const float4*)qrow)[8 + quad * 2];
        const float4 q3 = ((const float4*)qrow)[8 + quad * 2 + 1];
        aq0[0] = f2bf(q0.x * 0.125f); aq0[1] = f2bf(q0.y * 0.125f);
        aq0[2] = f2bf(q0.z * 0.125f); aq0[3] = f2bf(q0.w * 0.125f);
        aq0[4] = f2bf(q1.x * 0.125f); aq0[5] = f2bf(q1.y * 0.125f);
        aq0[6] = f2bf(q1.z * 0.125f); aq0[7] = f2bf(q1.w * 0.125f);
        aq1[0] = f2bf(q2.x * 0.125f); aq1[1] = f2bf(q2.y * 0.125f);
        aq1[2] = f2bf(q2.z * 0.125f); aq1[3] = f2bf(q2.w * 0.125f);
        aq1[4] = f2bf(q3.x * 0.125f); aq1[5] = f2bf(q3.y * 0.125f);
        aq1[6] = f2bf(q3.z * 0.125f); aq1[7] = f2bf(q3.w * 0.125f);
    }

    bf16x8 vfrag[4][4];
    {
        const float* vbase = V + ((size_t)(b * NTOK) + j0 + quad * 8) * HID + h * HD + ln15;
        #pragma unroll
        for (int dt = 0; dt < 4; ++dt)
            #pragma unroll
            for (int kt = 0; kt < 4; ++kt)
                #pragma unroll
                for (int jj = 0; jj < 8; ++jj)
                    vfrag[dt][kt][jj] = f2bf(vbase[(size_t)(kt * 32 + jj) * HID + dt * 16]);
    }

    #pragma unroll 4
    for (int it = 0; it < 32; ++it) {
        const int flat = it * 64 + lane;
        const int jl = flat >> 4, dq = flat & 15;
        const float4 kv = ((const float4*)(K + ((size_t)(b * NTOK) + j0 + jl) * HID + h * HD))[dq];
        bf16x4 ks;
        ks[0] = f2bf(kv.x); ks[1] = f2bf(kv.y); ks[2] = f2bf(kv.z); ks[3] = f2bf(kv.w);
        *(bf16x4*)&Kt[w][jl * KT_STRIDE + dq * 4] = ks;
    }

    f32x4 s[8];
    #pragma unroll
    for (int nt = 0; nt < 8; ++nt) {
        const int krow = nt * 16 + ln15;
        const bf16x8 bk0 = *(const bf16x8*)&Kt[w][krow * KT_STRIDE + quad * 8];
        const bf16x8 bk1 = *(const bf16x8*)&Kt[w][krow * KT_STRIDE + 32 + quad * 8];
        f32x4 acc = (f32x4){0.f, 0.f, 0.f, 0.f};
        acc = __builtin_amdgcn_mfma_f32_16x16x32_bf16(aq0, bk0, acc, 0, 0, 0);
        acc = __builtin_amdgcn_mfma_f32_16x16x32_bf16(aq1, bk1, acc, 0, 0, 0);
        s[nt] = acc;
    }

    #pragma unroll
    for (int nt = 0; nt < 8; ++nt)
        #pragma unroll
        for (int r = 0; r < 4; ++r)
            s[nt][r] += bpre[nt][r];

    float p[8][4], m_r[4], l_r[4];
    #pragma unroll
    for (int r = 0; r < 4; ++r) {
        float mx = s[0][r];
        #pragma unroll
        for (int nt = 1; nt < 8; ++nt) mx = fmaxf(mx, s[nt][r]);
        #pragma unroll
        for (int off = 1; off < 16; off <<= 1) mx = fmaxf(mx, __shfl_xor(mx, off, 64));
        float rs = 0.f;
        #pragma unroll
        for (int nt = 0; nt < 8; ++nt) { p[nt][r] = __expf(s[nt][r] - mx); rs += p[nt][r]; }
        #pragma unroll
        for (int off = 1; off < 16; off <<= 1) rs += __shfl_xor(rs, off, 64);
        m_r[r] = mx; l_r[r] = rs;
    }

    #pragma unroll
    for (int nt = 0; nt < 8; ++nt)
        #pragma unroll
        for (int r = 0; r < 4; ++r)
            Pl[w][(quad * 4 + r) * PL_STRIDE + nt * 16 + ln15] = f2bf(p[nt][r]);

    bf16x8 ap[4];
    #pragma unroll
    for (int kt = 0; kt < 4; ++kt)
        ap[kt] = *(const bf16x8*)&Pl[w][ln15 * PL_STRIDE + kt * 32 + quad * 8];

    f32x4 o_acc[4];
    #pragma unroll
    for (int dt = 0; dt < 4; ++dt) o_acc[dt] = (f32x4){0.f, 0.f, 0.f, 0.f};
    #pragma unroll
    for (int dt = 0; dt < 4; ++dt)
        #pragma unroll
        for (int kt = 0; kt < 4; ++kt)
            o_acc[dt] = __builtin_amdgcn_mfma_f32_16x16x32_bf16(ap[kt], vfrag[dt][kt], o_acc[dt], 0, 0, 0);

    #pragma unroll
    for (int dt = 0; dt < 4; ++dt)
        #pragma unroll
        for (int r = 0; r < 4; ++r)
            Om[w][quad * 4 + r][dt * 16 + ln15] = o_acc[dt][r];
    if (ln15 == 0) {
        #pragma unroll
        for (int r = 0; r < 4; ++r)
            ml[w][quad * 4 + r] = make_float2(m_r[r], l_r[r]);
    }
    __syncthreads();

    {
        const int row = t >> 4;
        const int dbase = (t & 15) * 4;
        float M = ml[0][row].x;
        #pragma unroll
        for (int s4 = 1; s4 < 4; ++s4) M = fmaxf(M, ml[s4][row].x);
        float L = 0.f, sc[4];
        #pragma unroll
        for (int s4 = 0; s4 < 4; ++s4) {
            sc[s4] = __expf(ml[s4][row].x - M);
            L += ml[s4][row].y * sc[s4];
        }
        const float inv = 1.0f / L;
        float4 v4;
        v4.x = (Om[0][row][dbase + 0] * sc[0] + Om[1][row][dbase + 0] * sc[1] +
                Om[2][row][dbase + 0] * sc[2] + Om[3][row][dbase + 0] * sc[3]) * inv;
        v4.y = (Om[0][row][dbase + 1] * sc[0] + Om[1][row][dbase + 1] * sc[1] +
                Om[2][row][dbase + 1] * sc[2] + Om[3][row][dbase + 1] * sc[3]) * inv;
        v4.z = (Om[0][row][dbase + 2] * sc[0] + Om[1][row][dbase + 2] * sc[1] +
                Om[2][row][dbase + 2] * sc[2] + Om[3][row][dbase + 2] * sc[3]) * inv;
        v4.w = (Om[0][row][dbase + 3] * sc[0] + Om[1][row][dbase + 3] * sc[1] +
                Om[2][row][dbase + 3] * sc[2] + Om[3][row][dbase + 3] * sc[3]) * inv;
        *(float4*)(Og + ((size_t)(b * NTOK) + i0 + row) * HID + h * HD + dbase) = v4;
    }
}

// ---------------------------------------------------------------------------
// Stage D: pure GEMM out = O@Wo + bo.
// ---------------------------------------------------------------------------
__global__ __launch_bounds__(256) void pga_outproj(
    const float* __restrict__ O,
    const float* __restrict__ Wo, const float* __restrict__ bo,
    float* __restrict__ out)
{
    __shared__ float xs[4][HID];
    const int m0 = blockIdx.x * 4;
    const int t = threadIdx.x;

    #pragma unroll
    for (int r = 0; r < 4; ++r)
        xs[r][t] = O[(size_t)(m0 + r) * HID + t];
    __syncthreads();

    const int cg = t & 63;
    const int rg = t >> 6;
    float4 acc = ((const float4*)bo)[cg];

    const float4* W4 = (const float4*)Wo;
    const float4* xrow = (const float4*)xs[rg];
    #pragma unroll 2
    for (int kq = 0; kq < 64; ++kq) {
        const float4 w0 = W4[(4 * kq + 0) * 64 + cg];
        const float4 w1 = W4[(4 * kq + 1) * 64 + cg];
        const float4 w2 = W4[(4 * kq + 2) * 64 + cg];
        const float4 w3 = W4[(4 * kq + 3) * 64 + cg];
        const float4 xv = xrow[kq];
        acc.x = fmaf(xv.x, w0.x, fmaf(xv.y, w1.x, fmaf(xv.z, w2.x, fmaf(xv.w, w3.x, acc.x))));
        acc.y = fmaf(xv.x, w0.y, fmaf(xv.y, w1.y, fmaf(xv.z, w2.y, fmaf(xv.w, w3.y, acc.y))));
        acc.z = fmaf(xv.x, w0.z, fmaf(xv.y, w1.z, fmaf(xv.z, w2.z, fmaf(xv.w, w3.z, acc.z))));
        acc.w = fmaf(xv.x, w0.w, fmaf(xv.y, w1.w, fmaf(xv.z, w2.w, fmaf(xv.w, w3.w, acc.w))));
    }
    ((float4*)(out + (m0 + rg) * HID))[cg] = acc;
}

extern "C" void kernel_launch(void* const* d_in, const int* in_sizes, int n_in,
                              void* d_out, int out_size, void* d_ws, size_t ws_size,
                              hipStream_t stream) {
    const float* x   = (const float*)d_in[0];
    const int*   adj = (const int*)d_in[1];
    const float* Wq  = (const float*)d_in[2];
    const float* bq  = (const float*)d_in[3];
    const float* Wk  = (const float*)d_in[4];
    const float* bk  = (const float*)d_in[5];
    const float* Wv  = (const float*)d_in[6];
    const float* bv  = (const float*)d_in[7];
    const float* Wo  = (const float*)d_in[8];
    const float* bo  = (const float*)d_in[9];
    const float* Wp1 = (const float*)d_in[10];
    const float* bp1 = (const float*)d_in[11];
    const float* Wp2 = (const float*)d_in[12];
    const float* bp2 = (const float*)d_in[13];
    float* out = (float*)d_out;

    // ws layout (floats). A dies after pga_bias and is reused as the
    // normalized O buffer written by pga_attn (same-stream ordering).
    float* ws   = (float*)d_ws;
    float* Q    = ws;
    float* K    = ws + 262144;
    float* V    = ws + 2 * 262144;
    float* A    = ws + 3 * 262144;     // -> O (normalized attn output)
    float* Brow = ws + 4 * 262144;
    float* bias = ws + 5 * 262144;     // 2097152 floats

    pga_proj5<<<dim3(64, 5), 256, 0, stream>>>(x, Wq, bq, Wk, bk, Wv, bv,
                                               Wp1, bp1, Q, K, V, A, Brow);
    pga_bias<<<1024, 320, 0, stream>>>(A, Brow, Wp2, bp2, adj, bias);
    pga_attn<<<256, 256, 0, stream>>>(Q, K, V, bias, A);
    pga_outproj<<<256, 256, 0, stream>>>(A, Wo, bo, out);
}